// Round 11
// baseline (188.969 us; speedup 1.0000x reference)
//
#include <hip/hip_runtime.h>

// ---------------------------------------------------------------------------
// Problem constants
#define BQ 2048
#define NS 32768
#define DIM 256
#define NROWS (NS + BQ)

// Fast-path (MFMA) tiling: block = 128q x 128s, 4 waves, wave = 32q x 128s
// (2 A-frags x 8 B-frags, acc = 64 AGPR; VGPR 84 + 64 = 148 -> 3 waves/SIMD).
#define BMQ 128                // queries per block
#define BNS 128                // supports per block
#define BK 32                  // K per stage
#define NST (DIM / BK)         // 8 pipeline stages
#define GY (NS / BNS)          // 256 chunks per query
// Certification: score = s2 - 2*(xh . sh), RTN f16. EPS = 0.08 ~ 8 sigma of
// per-pair error (validated: absmax 0 at R9/R10). Flagged queries resolved by
// in-block candidate-chunk exact rescan: any exact argmin's chunk c satisfies
// pv1[c] <= bv1 + EPS (per-score |approx-exact| <= EPS/2).
#define EPS 0.08f

typedef _Float16 f16;
typedef _Float16 f16x4 __attribute__((ext_vector_type(4)));
typedef _Float16 f16x8 __attribute__((ext_vector_type(8)));
typedef float    f32x4 __attribute__((ext_vector_type(4)));

// ---------------------------------------------------------------------------
// global->LDS DMA, 16B/lane; LDS dest = wave-uniform base + lane*16.
// Per-lane source address carries the XOR swizzle (R7-verified: 0 conflicts).
// ---------------------------------------------------------------------------
__device__ __forceinline__ void gload16(const f16* g, f16* l) {
    __builtin_amdgcn_global_load_lds(
        (const __attribute__((address_space(1))) unsigned int*)g,
        (__attribute__((address_space(3))) unsigned int*)l, 16, 0, 0);
}

// Swizzled fragment pointer: rows of 32 f16 (64 B), cell q stored at
// q ^ ((row>>1)&3).
__device__ __forceinline__ const f16x8* fragp(const f16* base, int row, int q) {
    return (const f16x8*)(base + row * 32 + ((q ^ ((row >> 1) & 3)) << 3));
}

// ---------------------------------------------------------------------------
// Kernel 1: x -> f16 xh, sup -> f16 sh, s2 exact fp32. One wave per row.
// ---------------------------------------------------------------------------
__global__ __launch_bounds__(256) void convert_kernel(
    const float* __restrict__ x, const float* __restrict__ sup,
    f16* __restrict__ xh, f16* __restrict__ sh, float* __restrict__ s2) {
    const int wave = threadIdx.x >> 6, lane = threadIdx.x & 63;
    const int row = blockIdx.x * 4 + wave;
    if (row < NS) {
        float4 v = ((const float4*)(sup + (size_t)row * DIM))[lane];
        f16x4 hi;
        hi[0] = (f16)v.x; hi[1] = (f16)v.y; hi[2] = (f16)v.z; hi[3] = (f16)v.w;
        *(f16x4*)(sh + (size_t)row * DIM + lane * 4) = hi;
        float sum = v.x * v.x + v.y * v.y + v.z * v.z + v.w * v.w;
#pragma unroll
        for (int off = 32; off > 0; off >>= 1) sum += __shfl_xor(sum, off);
        if (lane == 0) s2[row] = sum;
    } else {
        const int q = row - NS;
        float4 v = ((const float4*)(x + (size_t)q * DIM))[lane];
        f16x4 hi;
        hi[0] = (f16)v.x; hi[1] = (f16)v.y; hi[2] = (f16)v.z; hi[3] = (f16)v.w;
        *(f16x4*)(xh + (size_t)q * DIM + lane * 4) = hi;
    }
}

// ---------------------------------------------------------------------------
// Kernel 2: single-term f16 MFMA GEMM + top-2 argmin. 128x128 block tile,
// double-buffered DMA (4 calls/wave/stage), 8 barriers/block, grid 16x256.
// (R10-proven: 64 us, VGPR 84, 0 bank conflicts.)
// ---------------------------------------------------------------------------
__global__ __launch_bounds__(256) void knn_mfma(
    const f16* __restrict__ xh, const f16* __restrict__ sh,
    const float* __restrict__ s2g,
    float* __restrict__ pv1, float* __restrict__ pv2, int* __restrict__ pi1) {
    __shared__ f16 T[2][2][BMQ * 32];   // [buf][X|S][row*32], 32 KB total

    const int tid  = threadIdx.x;
    const int lane = tid & 63, wid = tid >> 6;
    const int l16  = lane & 15, quad = lane >> 4;
    const int m0   = blockIdx.x * BMQ;
    const int n0   = blockIdx.y * BNS;

    // DMA per-lane swizzled source offset (one call = 16 rows x 32 f16 = 1KB)
    const int rl = lane >> 2;
    const int qs = (lane & 3) ^ ((rl >> 1) & 3);
    const size_t srcoff = (size_t)rl * DIM + qs * 8;

    // wave w stages X rows 32w..32w+31 and S rows 32w..32w+31 (2 calls each)
    const f16* px0 = xh + (size_t)(m0 + wid * 32) * DIM + srcoff;
    const f16* px1 = px0 + (size_t)16 * DIM;
    const f16* ps0 = sh + (size_t)(n0 + wid * 32) * DIM + srcoff;
    const f16* ps1 = ps0 + (size_t)16 * DIM;
    const int dX = wid * 1024;          // f16 offset: row 32w

    f32x4 acc[2][8];
#pragma unroll
    for (int fi = 0; fi < 2; ++fi)
#pragma unroll
        for (int fj = 0; fj < 8; ++fj) acc[fi][fj] = (f32x4){0.f, 0.f, 0.f, 0.f};

    // prologue prefetch stage 0
    gload16(px0, &T[0][0][dX]);
    gload16(px1, &T[0][0][dX + 512]);
    gload16(ps0, &T[0][1][dX]);
    gload16(ps1, &T[0][1][dX + 512]);

    for (int s = 0; s < NST; ++s) {
        __syncthreads();                  // drains DMA for stage s
        if (s + 1 < NST) {
            const int b = (s + 1) & 1, k0 = (s + 1) * BK;
            gload16(px0 + k0, &T[b][0][dX]);
            gload16(px1 + k0, &T[b][0][dX + 512]);
            gload16(ps0 + k0, &T[b][1][dX]);
            gload16(ps1 + k0, &T[b][1][dX + 512]);
        }
        const f16* TX = &T[s & 1][0][0];
        const f16* TS = &T[s & 1][1][0];

        f16x8 A0 = *fragp(TX, wid * 32 + l16,      quad);
        f16x8 A1 = *fragp(TX, wid * 32 + 16 + l16, quad);
#pragma unroll
        for (int fj = 0; fj < 8; ++fj) {
            f16x8 B = *fragp(TS, fj * 16 + l16, quad);
            acc[0][fj] = __builtin_amdgcn_mfma_f32_16x16x32_f16(A0, B, acc[0][fj], 0, 0, 0);
            acc[1][fj] = __builtin_amdgcn_mfma_f32_16x16x32_f16(A1, B, acc[1][fj], 0, 0, 0);
        }
    }

    // epilogue: per-slot top-2 over 8 cols, 16-lane merge, write partials
    float s2v[8];
#pragma unroll
    for (int fj = 0; fj < 8; ++fj) s2v[fj] = s2g[n0 + fj * 16 + l16];
#pragma unroll
    for (int fi = 0; fi < 2; ++fi)
#pragma unroll
        for (int rg = 0; rg < 4; ++rg) {
            float bv1 = 3.4e38f, bv2 = 3.4e38f; int bi = 0;
#pragma unroll
            for (int fj = 0; fj < 8; ++fj) {
                float s = fmaf(-2.f, acc[fi][fj][rg], s2v[fj]);
                bv2 = fminf(bv2, fmaxf(bv1, s));
                bi  = (s < bv1) ? (n0 + fj * 16 + l16) : bi;
                bv1 = fminf(bv1, s);
            }
#pragma unroll
            for (int m = 1; m < 16; m <<= 1) {
                float ov1 = __shfl_xor(bv1, m);
                float ov2 = __shfl_xor(bv2, m);
                int   oi  = __shfl_xor(bi, m);
                float nb2 = fminf(fminf(bv2, ov2), fmaxf(bv1, ov1));
                bi  = (ov1 < bv1) ? oi : bi;
                bv1 = fminf(bv1, ov1);
                bv2 = nb2;
            }
            if (l16 == 0) {
                const int row = m0 + wid * 32 + fi * 16 + quad * 4 + rg;
                pv1[(size_t)row * GY + blockIdx.y] = bv1;
                pv2[(size_t)row * GY + blockIdx.y] = bv2;
                pi1[(size_t)row * GY + blockIdx.y] = bi;
            }
        }
}

// ---------------------------------------------------------------------------
// Kernel 3 (fused): merge GY=256 chunk-top2s (one chunk per thread), parallel
// is64 label detect (ballot), and — if the gap is uncertified — in-block
// exact fp32 rescan of candidate chunks, then one-hot write.
// ---------------------------------------------------------------------------
__global__ __launch_bounds__(256) void finalize_fused(
    const float* __restrict__ pv1, const float* __restrict__ pv2,
    const int* __restrict__ pi1,
    const float* __restrict__ x, const float* __restrict__ sup,
    const float* __restrict__ s2, const int* __restrict__ labels,
    const int* __restrict__ ncp, int* __restrict__ out) {
    const int q = blockIdx.x, tid = threadIdx.x;
    const int lane = tid & 63, w = tid >> 6;
    __shared__ float sv1[4], sv2[4];
    __shared__ int   si[4];
    __shared__ float s_bv1, s_bv2;
    __shared__ int   s_bi, s_is64, s_label;
    __shared__ int   cand[GY];
    __shared__ int   ncand;
    __shared__ float fwv[4];
    __shared__ int   fwi[4];

    // ---- each thread owns exactly one chunk ----
    float bv1 = pv1[(size_t)q * GY + tid];
    float bv2 = pv2[(size_t)q * GY + tid];
    int   bi  = pi1[(size_t)q * GY + tid];
    const float myv1 = bv1;
#pragma unroll
    for (int m = 1; m < 64; m <<= 1) {
        float ov1 = __shfl_xor(bv1, m);
        float ov2 = __shfl_xor(bv2, m);
        int   oi  = __shfl_xor(bi, m);
        float nb2 = fminf(fminf(bv2, ov2), fmaxf(bv1, ov1));
        bi  = (ov1 < bv1) ? oi : bi;
        bv1 = fminf(bv1, ov1);
        bv2 = nb2;
    }
    if (lane == 0) { sv1[w] = bv1; sv2[w] = bv2; si[w] = bi; }
    // ---- parallel is64 detect: wave 0 probes all odd int32 words ----
    if (w == 0) {
        unsigned long long ball = __ballot(labels[2 * lane + 1] == 0);
        if (lane == 0) s_is64 = (ball == ~0ULL) ? 1 : 0;
    }
    if (tid == 0) ncand = 0;
    __syncthreads();
    if (tid == 0) {
        float fb1 = sv1[0], fb2 = sv2[0]; int fbi = si[0];
#pragma unroll
        for (int t = 1; t < 4; ++t) {
            float nb2 = fminf(fminf(fb2, sv2[t]), fmaxf(fb1, sv1[t]));
            fbi = (sv1[t] < fb1) ? si[t] : fbi;
            fb1 = fminf(fb1, sv1[t]);
            fb2 = nb2;
        }
        s_bv1 = fb1; s_bv2 = fb2; s_bi = fbi;
    }
    __syncthreads();

    const int nc = ncp[0];
    if (s_bv2 - s_bv1 > EPS) {
        // certified: approx argmin is exact
        if (tid == 0)
            s_label = s_is64 ? labels[2 * s_bi] : labels[s_bi];
        __syncthreads();
        const int lbl = s_label;
        for (int c = tid; c < nc; c += 256)
            out[q * nc + c] = (c == lbl) ? 1 : 0;
        return;
    }

    // ---- uncertified: exact rescan of candidate chunks ----
    if (myv1 <= s_bv1 + EPS) {
        int slot = atomicAdd(&ncand, 1);
        cand[slot] = tid;
    }
    __syncthreads();
    const int ncd = ncand;
    float best = 3.4e38f; int bix = 0x7fffffff;
    for (int ci = 0; ci < ncd; ++ci) {
        const int base = cand[ci] * BNS + w * 32;
        const float4* xp = (const float4*)(x + (size_t)q * DIM);
        const float4 xv = xp[lane];
#pragma unroll 4
        for (int r = 0; r < 32; ++r) {
            const int n = base + r;
            float4 sv = ((const float4*)(sup + (size_t)n * DIM))[lane];
            float d = fmaf(sv.x, xv.x,
                      fmaf(sv.y, xv.y,
                      fmaf(sv.z, xv.z, sv.w * xv.w)));
#pragma unroll
            for (int m = 32; m > 0; m >>= 1) d += __shfl_xor(d, m);
            float sc = s2[n] - 2.f * d;
            if (sc < best || (sc == best && n < bix)) { best = sc; bix = n; }
        }
    }
    if (lane == 0) { fwv[w] = best; fwi[w] = bix; }
    __syncthreads();
    if (tid == 0) {
        float fb = fwv[0]; int fx = fwi[0];
#pragma unroll
        for (int t = 1; t < 4; ++t)
            if (fwv[t] < fb || (fwv[t] == fb && fwi[t] < fx)) { fb = fwv[t]; fx = fwi[t]; }
        s_label = s_is64 ? labels[2 * fx] : labels[fx];
    }
    __syncthreads();
    const int lbl = s_label;
    for (int c = tid; c < nc; c += 256)
        out[q * nc + c] = (c == lbl) ? 1 : 0;
}

// ===========================================================================
// Slow path (ws too small): proven R3 fp32 kernels.
// ===========================================================================
#define SBM 128
#define SBN 128
#define SBK 16
#define SNT 4
#define SGY (NS / (SBN * SNT))
#define SLDT (SBM + 4)

__global__ __launch_bounds__(256) void s2_kernel(const float* __restrict__ s,
                                                 float* __restrict__ s2) {
    int wave = threadIdx.x >> 6, lane = threadIdx.x & 63;
    int row = blockIdx.x * 4 + wave;
    const float4* p = (const float4*)(s + (size_t)row * DIM);
    float4 v = p[lane];
    float sum = v.x * v.x + v.y * v.y + v.z * v.z + v.w * v.w;
#pragma unroll
    for (int off = 32; off > 0; off >>= 1) sum += __shfl_xor(sum, off);
    if (lane == 0) s2[row] = sum;
}

__global__ __launch_bounds__(256) void knn_f32(const float* __restrict__ x,
                                               const float* __restrict__ sup,
                                               const float* __restrict__ s2g,
                                               float* __restrict__ pvals,
                                               int* __restrict__ pidx) {
    __shared__ float Xs[SBK][SLDT];
    __shared__ float Bs[SBK][SLDT];
    const int tid = threadIdx.x;
    const int tx = tid & 15, ty = tid >> 4;
    const int m0 = blockIdx.x * SBM, by = blockIdx.y;
    const int srow = tid >> 2, skq = (tid & 3) * 4;
    float rmin[8]; int ridx[8];
#pragma unroll
    for (int i = 0; i < 8; ++i) { rmin[i] = 3.4e38f; ridx[i] = 0x7fffffff; }
    const float* xr0 = x + (size_t)(m0 + srow) * DIM + skq;
    const float* xr1 = x + (size_t)(m0 + 64 + srow) * DIM + skq;
    for (int nt = 0; nt < SNT; ++nt) {
        const int n0 = (by * SNT + nt) * SBN;
        const float* sr0 = sup + (size_t)(n0 + srow) * DIM + skq;
        const float* sr1 = sup + (size_t)(n0 + 64 + srow) * DIM + skq;
        float acc[8][8];
#pragma unroll
        for (int i = 0; i < 8; ++i)
#pragma unroll
            for (int j = 0; j < 8; ++j) acc[i][j] = 0.0f;
        for (int kt = 0; kt < DIM / SBK; ++kt) {
            const int k0 = kt * SBK;
            float4 xv0 = *(const float4*)(xr0 + k0);
            float4 xv1 = *(const float4*)(xr1 + k0);
            float4 sv0 = *(const float4*)(sr0 + k0);
            float4 sv1 = *(const float4*)(sr1 + k0);
            __syncthreads();
            Xs[skq + 0][srow] = xv0.x; Xs[skq + 1][srow] = xv0.y;
            Xs[skq + 2][srow] = xv0.z; Xs[skq + 3][srow] = xv0.w;
            Xs[skq + 0][64 + srow] = xv1.x; Xs[skq + 1][64 + srow] = xv1.y;
            Xs[skq + 2][64 + srow] = xv1.z; Xs[skq + 3][64 + srow] = xv1.w;
            Bs[skq + 0][srow] = sv0.x; Bs[skq + 1][srow] = sv0.y;
            Bs[skq + 2][srow] = sv0.z; Bs[skq + 3][srow] = sv0.w;
            Bs[skq + 0][64 + srow] = sv1.x; Bs[skq + 1][64 + srow] = sv1.y;
            Bs[skq + 2][64 + srow] = sv1.z; Bs[skq + 3][64 + srow] = sv1.w;
            __syncthreads();
#pragma unroll
            for (int k = 0; k < SBK; ++k) {
                float4 a0 = *(const float4*)&Xs[k][ty * 4];
                float4 a1 = *(const float4*)&Xs[k][64 + ty * 4];
                float4 b0 = *(const float4*)&Bs[k][tx * 4];
                float4 b1 = *(const float4*)&Bs[k][64 + tx * 4];
                float a[8] = {a0.x, a0.y, a0.z, a0.w, a1.x, a1.y, a1.z, a1.w};
                float b[8] = {b0.x, b0.y, b0.z, b0.w, b1.x, b1.y, b1.z, b1.w};
#pragma unroll
                for (int i = 0; i < 8; ++i)
#pragma unroll
                    for (int j = 0; j < 8; ++j)
                        acc[i][j] = fmaf(a[i], b[j], acc[i][j]);
            }
        }
        const int nb0 = n0 + tx * 4, nb1 = n0 + 64 + tx * 4;
        float4 s20 = *(const float4*)(s2g + nb0);
        float4 s21 = *(const float4*)(s2g + nb1);
        float s2a[8] = {s20.x, s20.y, s20.z, s20.w, s21.x, s21.y, s21.z, s21.w};
        int nca[8] = {nb0, nb0 + 1, nb0 + 2, nb0 + 3, nb1, nb1 + 1, nb1 + 2, nb1 + 3};
#pragma unroll
        for (int i = 0; i < 8; ++i)
#pragma unroll
            for (int j = 0; j < 8; ++j) {
                float sc = fmaf(-2.0f, acc[i][j], s2a[j]);
                if (sc < rmin[i] || (sc == rmin[i] && nca[j] < ridx[i])) {
                    rmin[i] = sc; ridx[i] = nca[j];
                }
            }
    }
    __syncthreads();
    float* redv = (float*)Xs;
    int* redi = (int*)Bs;
#pragma unroll
    for (int i = 0; i < 8; ++i) {
        int mrow = (i < 4) ? (ty * 4 + i) : (64 + ty * 4 + (i - 4));
        redv[mrow * 16 + tx] = rmin[i];
        redi[mrow * 16 + tx] = ridx[i];
    }
    __syncthreads();
    if (tid < SBM) {
        float best = redv[tid * 16];
        int bi = redi[tid * 16];
#pragma unroll
        for (int t = 1; t < 16; ++t) {
            float v = redv[tid * 16 + t];
            int ix = redi[tid * 16 + t];
            if (v < best || (v == best && ix < bi)) { best = v; bi = ix; }
        }
        pvals[(size_t)(m0 + tid) * SGY + by] = best;
        pidx[(size_t)(m0 + tid) * SGY + by] = bi;
    }
}

__global__ __launch_bounds__(64) void finalize_f32(const float* __restrict__ pvals,
                                                   const int* __restrict__ pidx,
                                                   const int* __restrict__ labels,
                                                   const int* __restrict__ ncp,
                                                   int* __restrict__ out) {
    const int b = blockIdx.x, lane = threadIdx.x;
    float v = pvals[(size_t)b * SGY + lane];
    int ix = pidx[(size_t)b * SGY + lane];
#pragma unroll
    for (int off = 32; off > 0; off >>= 1) {
        float ov = __shfl_xor(v, off);
        int oi = __shfl_xor(ix, off);
        if (ov < v || (ov == v && oi < ix)) { v = ov; ix = oi; }
    }
    bool is64 = true;
    for (int i = 1; i < 128; i += 2)
        if (labels[i] != 0) { is64 = false; break; }
    const int lbl = is64 ? labels[2 * ix] : labels[ix];
    const int nc = ncp[0];
    for (int c = lane; c < nc; c += 64)
        out[b * nc + c] = (c == lbl) ? 1 : 0;
}

// ---------------------------------------------------------------------------
extern "C" void kernel_launch(void* const* d_in, const int* in_sizes, int n_in,
                              void* d_out, int out_size, void* d_ws, size_t ws_size,
                              hipStream_t stream) {
    const float* x      = (const float*)d_in[0];
    const float* sup    = (const float*)d_in[1];
    const int*   labels = (const int*)d_in[2];
    const int*   ncp    = (const int*)d_in[3];
    int* out = (int*)d_out;

    // fast-path workspace layout (~25 MB)
    char* p = (char*)d_ws;
    float* s2  = (float*)p;               p += (size_t)NS * 4;
    float* pv1 = (float*)p;               p += (size_t)BQ * GY * 4;
    float* pv2 = (float*)p;               p += (size_t)BQ * GY * 4;
    int*   pi1 = (int*)p;                 p += (size_t)BQ * GY * 4;
    f16*   xh  = (f16*)p;                 p += (size_t)BQ * DIM * 2;
    f16*   sh  = (f16*)p;                 p += (size_t)NS * DIM * 2;
    const size_t need = (size_t)(p - (char*)d_ws);

    if (ws_size >= need) {
        convert_kernel<<<NROWS / 4, 256, 0, stream>>>(x, sup, xh, sh, s2);
        dim3 grid(BQ / BMQ, GY);
        knn_mfma<<<grid, 256, 0, stream>>>(xh, sh, s2, pv1, pv2, pi1);
        finalize_fused<<<BQ, 256, 0, stream>>>(pv1, pv2, pi1, x, sup, s2,
                                               labels, ncp, out);
    } else {
        // slow path: proven fp32 pipeline (R3)
        float* ss2   = (float*)d_ws;
        float* pvals = ss2 + NS;
        int*   pidx  = (int*)(pvals + (size_t)BQ * SGY);
        s2_kernel<<<NS / 4, 256, 0, stream>>>(sup, ss2);
        dim3 sgrid(BQ / SBM, SGY);
        knn_f32<<<sgrid, 256, 0, stream>>>(x, sup, ss2, pvals, pidx);
        finalize_f32<<<BQ, 64, 0, stream>>>(pvals, pidx, labels, ncp, out);
    }
}

// Round 12
// 158.073 us; speedup vs baseline: 1.1955x; 1.1955x over previous
//
#include <hip/hip_runtime.h>

// ---------------------------------------------------------------------------
// Problem constants
#define BQ 2048
#define NS 32768
#define DIM 256
#define NROWS (NS + BQ)

// Fast-path (MFMA) tiling: block = 128q x 128s, 4 waves, wave = 32q x 128s
// (2 A-frags x 8 B-frags, acc = 64 AGPR; VGPR ~84 + 64 -> 3 waves/SIMD).
#define BMQ 128                // queries per block
#define BNS 128                // supports per block
#define BK 32                  // K per stage
#define NST (DIM / BK)         // 8 pipeline stages
#define GY (NS / BNS)          // 256 chunks per query
// Certification: score = s2 - 2*(xh . sh), RTN f16. EPS = 0.08 ~ 8 sigma of
// per-pair error (validated: absmax 0 at R9/R10/R11). Flagged queries go to
// the candidate-chunk exact rescan (chunk c can hold the exact argmin only if
// pv1[c] <= qbest + EPS, since per-score |approx-exact| <= EPS/2).
#define EPS 0.08f
#define FBCH GY                // fallback chunk granularity == partial chunks

typedef _Float16 f16;
typedef _Float16 f16x4 __attribute__((ext_vector_type(4)));
typedef _Float16 f16x8 __attribute__((ext_vector_type(8)));
typedef float    f32x4 __attribute__((ext_vector_type(4)));

// ---------------------------------------------------------------------------
// global->LDS DMA, 16B/lane; LDS dest = wave-uniform base + lane*16.
// Per-lane source address carries the XOR swizzle (R7-verified: 0 conflicts).
// ---------------------------------------------------------------------------
__device__ __forceinline__ void gload16(const f16* g, f16* l) {
    __builtin_amdgcn_global_load_lds(
        (const __attribute__((address_space(1))) unsigned int*)g,
        (__attribute__((address_space(3))) unsigned int*)l, 16, 0, 0);
}

// Swizzled fragment pointer: rows of 32 f16 (64 B), cell q stored at
// q ^ ((row>>1)&3).
__device__ __forceinline__ const f16x8* fragp(const f16* base, int row, int q) {
    return (const f16x8*)(base + row * 32 + ((q ^ ((row >> 1) & 3)) << 3));
}

// ---------------------------------------------------------------------------
// Kernel 1: x -> f16 xh, sup -> f16 sh, s2 exact fp32. One wave per row.
// Block 0 thread 0 zeroes fb_cnt.
// ---------------------------------------------------------------------------
__global__ __launch_bounds__(256) void convert_kernel(
    const float* __restrict__ x, const float* __restrict__ sup,
    f16* __restrict__ xh, f16* __restrict__ sh,
    float* __restrict__ s2, int* __restrict__ fb_cnt) {
    if (blockIdx.x == 0 && threadIdx.x == 0) *fb_cnt = 0;
    const int wave = threadIdx.x >> 6, lane = threadIdx.x & 63;
    const int row = blockIdx.x * 4 + wave;
    if (row < NS) {
        float4 v = ((const float4*)(sup + (size_t)row * DIM))[lane];
        f16x4 hi;
        hi[0] = (f16)v.x; hi[1] = (f16)v.y; hi[2] = (f16)v.z; hi[3] = (f16)v.w;
        *(f16x4*)(sh + (size_t)row * DIM + lane * 4) = hi;
        float sum = v.x * v.x + v.y * v.y + v.z * v.z + v.w * v.w;
#pragma unroll
        for (int off = 32; off > 0; off >>= 1) sum += __shfl_xor(sum, off);
        if (lane == 0) s2[row] = sum;
    } else {
        const int q = row - NS;
        float4 v = ((const float4*)(x + (size_t)q * DIM))[lane];
        f16x4 hi;
        hi[0] = (f16)v.x; hi[1] = (f16)v.y; hi[2] = (f16)v.z; hi[3] = (f16)v.w;
        *(f16x4*)(xh + (size_t)q * DIM + lane * 4) = hi;
    }
}

// ---------------------------------------------------------------------------
// Kernel 2: single-term f16 MFMA GEMM + top-2 argmin. 128x128 block tile.
// R12: TRIPLE-buffered DMA with manual "s_waitcnt vmcnt(4); s_barrier" —
// waits only for the stage being consumed; the just-issued next-next stage
// stays in flight across the barrier (2 stages of latency budget per batch).
// Final stage uses vmcnt(0). Each wave issues exactly 4 gload16/stage, so
// vmcnt(4) == "my 4 oldest done"; barrier then publishes all waves' LDS.
// ---------------------------------------------------------------------------
__global__ __launch_bounds__(256) void knn_mfma(
    const f16* __restrict__ xh, const f16* __restrict__ sh,
    const float* __restrict__ s2g,
    float* __restrict__ pv1, float* __restrict__ pv2, int* __restrict__ pi1) {
    __shared__ f16 T[3][2][BMQ * 32];   // [buf][X|S][row*32], 48 KB

    const int tid  = threadIdx.x;
    const int lane = tid & 63, wid = tid >> 6;
    const int l16  = lane & 15, quad = lane >> 4;
    const int m0   = blockIdx.x * BMQ;
    const int n0   = blockIdx.y * BNS;

    // DMA per-lane swizzled source offset (one call = 16 rows x 32 f16 = 1KB)
    const int rl = lane >> 2;
    const int qs = (lane & 3) ^ ((rl >> 1) & 3);
    const size_t srcoff = (size_t)rl * DIM + qs * 8;

    // wave w stages X rows 32w..32w+31 and S rows 32w..32w+31 (2 calls each)
    const f16* px0 = xh + (size_t)(m0 + wid * 32) * DIM + srcoff;
    const f16* px1 = px0 + (size_t)16 * DIM;
    const f16* ps0 = sh + (size_t)(n0 + wid * 32) * DIM + srcoff;
    const f16* ps1 = ps0 + (size_t)16 * DIM;
    const int dX = wid * 1024;          // f16 offset: row 32w

    f32x4 acc[2][8];
#pragma unroll
    for (int fi = 0; fi < 2; ++fi)
#pragma unroll
        for (int fj = 0; fj < 8; ++fj) acc[fi][fj] = (f32x4){0.f, 0.f, 0.f, 0.f};

    auto issue = [&](int s) {
        f16* bx = &T[s % 3][0][dX];
        f16* bs = &T[s % 3][1][dX];
        const int k0 = s * BK;
        gload16(px0 + k0, bx);
        gload16(px1 + k0, bx + 512);
        gload16(ps0 + k0, bs);
        gload16(ps1 + k0, bs + 512);
    };

    // prologue: 2 stages in flight
    issue(0);
    issue(1);

#pragma unroll
    for (int s = 0; s < NST; ++s) {
        if (s < NST - 1)
            asm volatile("s_waitcnt vmcnt(4)\n\ts_barrier" ::: "memory");
        else
            asm volatile("s_waitcnt vmcnt(0)\n\ts_barrier" ::: "memory");
        if (s + 2 < NST) issue(s + 2);

        const f16* TX = &T[s % 3][0][0];
        const f16* TS = &T[s % 3][1][0];
        f16x8 A0 = *fragp(TX, wid * 32 + l16,      quad);
        f16x8 A1 = *fragp(TX, wid * 32 + 16 + l16, quad);
#pragma unroll
        for (int fj = 0; fj < 8; ++fj) {
            f16x8 B = *fragp(TS, fj * 16 + l16, quad);
            acc[0][fj] = __builtin_amdgcn_mfma_f32_16x16x32_f16(A0, B, acc[0][fj], 0, 0, 0);
            acc[1][fj] = __builtin_amdgcn_mfma_f32_16x16x32_f16(A1, B, acc[1][fj], 0, 0, 0);
        }
    }

    // epilogue: per-slot top-2 over 8 cols, 16-lane merge, write partials
    float s2v[8];
#pragma unroll
    for (int fj = 0; fj < 8; ++fj) s2v[fj] = s2g[n0 + fj * 16 + l16];
#pragma unroll
    for (int fi = 0; fi < 2; ++fi)
#pragma unroll
        for (int rg = 0; rg < 4; ++rg) {
            float bv1 = 3.4e38f, bv2 = 3.4e38f; int bi = 0;
#pragma unroll
            for (int fj = 0; fj < 8; ++fj) {
                float s = fmaf(-2.f, acc[fi][fj][rg], s2v[fj]);
                bv2 = fminf(bv2, fmaxf(bv1, s));
                bi  = (s < bv1) ? (n0 + fj * 16 + l16) : bi;
                bv1 = fminf(bv1, s);
            }
#pragma unroll
            for (int m = 1; m < 16; m <<= 1) {
                float ov1 = __shfl_xor(bv1, m);
                float ov2 = __shfl_xor(bv2, m);
                int   oi  = __shfl_xor(bi, m);
                float nb2 = fminf(fminf(bv2, ov2), fmaxf(bv1, ov1));
                bi  = (ov1 < bv1) ? oi : bi;
                bv1 = fminf(bv1, ov1);
                bv2 = nb2;
            }
            if (l16 == 0) {
                const int row = m0 + wid * 32 + fi * 16 + quad * 4 + rg;
                pv1[(size_t)row * GY + blockIdx.y] = bv1;
                pv2[(size_t)row * GY + blockIdx.y] = bv2;
                pi1[(size_t)row * GY + blockIdx.y] = bi;
            }
        }
}

// ---------------------------------------------------------------------------
// Kernel 3 (R10-proven): merge GY chunk-top2s; one-hot; flag + list
// uncertified queries; store qbest for the candidate-chunk filter.
// ---------------------------------------------------------------------------
__global__ __launch_bounds__(128) void finalize2(
    const float* __restrict__ pv1, const float* __restrict__ pv2,
    const int* __restrict__ pi1, const int* __restrict__ labels,
    const int* __restrict__ ncp, int* __restrict__ out,
    int* __restrict__ fb_cnt, int* __restrict__ fb_list,
    float* __restrict__ qbest) {
    const int q = blockIdx.x, tid = threadIdx.x;
    __shared__ int s_label;
    if (tid < 64) {
        float bv1 = 3.4e38f, bv2 = 3.4e38f; int bi = 0;
        for (int t = tid; t < GY; t += 64) {
            float ov1 = pv1[(size_t)q * GY + t];
            float ov2 = pv2[(size_t)q * GY + t];
            int   oi  = pi1[(size_t)q * GY + t];
            float nb2 = fminf(fminf(bv2, ov2), fmaxf(bv1, ov1));
            bi  = (ov1 < bv1) ? oi : bi;
            bv1 = fminf(bv1, ov1);
            bv2 = nb2;
        }
#pragma unroll
        for (int m = 1; m < 64; m <<= 1) {
            float ov1 = __shfl_xor(bv1, m);
            float ov2 = __shfl_xor(bv2, m);
            int   oi  = __shfl_xor(bi, m);
            float nb2 = fminf(fminf(bv2, ov2), fmaxf(bv1, ov1));
            bi  = (ov1 < bv1) ? oi : bi;
            bv1 = fminf(bv1, ov1);
            bv2 = nb2;
        }
        if (tid == 0) {
            qbest[q] = bv1;
            if (bv2 - bv1 <= EPS) {
                int slot = atomicAdd(fb_cnt, 1);
                fb_list[slot] = q;
            }
            bool is64 = true;
            for (int i = 1; i < 128; i += 2)
                if (labels[i] != 0) { is64 = false; break; }
            s_label = is64 ? labels[2 * bi] : labels[bi];
        }
    }
    __syncthreads();
    const int nc = ncp[0], lbl = s_label;
    for (int c = tid; c < nc; c += 128)
        out[q * nc + c] = (c == lbl) ? 1 : 0;
}

// ---------------------------------------------------------------------------
// Kernel 4 (R10-proven): exact fp32 rescan for listed queries — candidate
// chunks only (pv1[q][c] <= qbest[q] + EPS). Skipped chunks write INF.
// ---------------------------------------------------------------------------
__global__ __launch_bounds__(256) void fallback_scan(
    const float* __restrict__ x, const float* __restrict__ sup,
    const float* __restrict__ s2, const int* __restrict__ fb_cnt,
    const int* __restrict__ fb_list, const float* __restrict__ qbest,
    const float* __restrict__ pv1,
    float* __restrict__ fb_v, int* __restrict__ fb_i) {
    const int nslots = *fb_cnt;
    const int chunk = blockIdx.x;          // 0..FBCH-1, 128 rows each
    const int tid = threadIdx.x, lane = tid & 63, w = tid >> 6;
    __shared__ float wv[4];
    __shared__ int   wi[4];
    for (int slot = blockIdx.y; slot < nslots; slot += gridDim.y) {
        const int q = fb_list[slot];
        if (pv1[(size_t)q * GY + chunk] > qbest[q] + EPS) {
            if (tid == 0) {
                fb_v[(size_t)q * FBCH + chunk] = 3.4e38f;
                fb_i[(size_t)q * FBCH + chunk] = 0x7fffffff;
            }
            __syncthreads();
            continue;
        }
        const float4 xv = ((const float4*)(x + (size_t)q * DIM))[lane];
        float best = 3.4e38f; int bi = 0x7fffffff;
        const int base = chunk * BNS + w * 32;
#pragma unroll 4
        for (int r = 0; r < 32; ++r) {
            const int n = base + r;
            float4 sv = ((const float4*)(sup + (size_t)n * DIM))[lane];
            float d = fmaf(sv.x, xv.x,
                      fmaf(sv.y, xv.y,
                      fmaf(sv.z, xv.z, sv.w * xv.w)));
#pragma unroll
            for (int m = 32; m > 0; m >>= 1) d += __shfl_xor(d, m);
            float sc = s2[n] - 2.f * d;
            if (sc < best) { best = sc; bi = n; }   // ascending n, strict <
        }
        if (lane == 0) { wv[w] = best; wi[w] = bi; }
        __syncthreads();
        if (tid == 0) {
            float bv = wv[0]; int bx = wi[0];
#pragma unroll
            for (int t = 1; t < 4; ++t)
                if (wv[t] < bv || (wv[t] == bv && wi[t] < bx)) { bv = wv[t]; bx = wi[t]; }
            fb_v[(size_t)q * FBCH + chunk] = bv;
            fb_i[(size_t)q * FBCH + chunk] = bx;
        }
        __syncthreads();
    }
}

// ---------------------------------------------------------------------------
// Kernel 5 (R10-proven): merge FBCH partials, rewrite one-hot.
// ---------------------------------------------------------------------------
__global__ __launch_bounds__(64) void fallback_merge(
    const int* __restrict__ fb_cnt, const int* __restrict__ fb_list,
    const float* __restrict__ fb_v, const int* __restrict__ fb_i,
    const int* __restrict__ labels, const int* __restrict__ ncp,
    int* __restrict__ out) {
    const int nslots = *fb_cnt;
    const int lane = threadIdx.x;
    for (int slot = blockIdx.x; slot < nslots; slot += gridDim.x) {
        const int q = fb_list[slot];
        float v = 3.4e38f; int ix = 0x7fffffff;
        for (int t = lane; t < FBCH; t += 64) {
            float ov = fb_v[(size_t)q * FBCH + t];
            int   oi = fb_i[(size_t)q * FBCH + t];
            if (ov < v || (ov == v && oi < ix)) { v = ov; ix = oi; }
        }
#pragma unroll
        for (int m = 1; m < 64; m <<= 1) {
            float ov = __shfl_xor(v, m);
            int   oi = __shfl_xor(ix, m);
            if (ov < v || (ov == v && oi < ix)) { v = ov; ix = oi; }
        }
        bool is64 = true;
        for (int i = 1; i < 128; i += 2)
            if (labels[i] != 0) { is64 = false; break; }
        const int lbl = is64 ? labels[2 * ix] : labels[ix];
        const int nc = ncp[0];
        for (int c = lane; c < nc; c += 64)
            out[q * nc + c] = (c == lbl) ? 1 : 0;
    }
}

// ===========================================================================
// Slow path (ws too small): proven R3 fp32 kernels.
// ===========================================================================
#define SBM 128
#define SBN 128
#define SBK 16
#define SNT 4
#define SGY (NS / (SBN * SNT))
#define SLDT (SBM + 4)

__global__ __launch_bounds__(256) void s2_kernel(const float* __restrict__ s,
                                                 float* __restrict__ s2) {
    int wave = threadIdx.x >> 6, lane = threadIdx.x & 63;
    int row = blockIdx.x * 4 + wave;
    const float4* p = (const float4*)(s + (size_t)row * DIM);
    float4 v = p[lane];
    float sum = v.x * v.x + v.y * v.y + v.z * v.z + v.w * v.w;
#pragma unroll
    for (int off = 32; off > 0; off >>= 1) sum += __shfl_xor(sum, off);
    if (lane == 0) s2[row] = sum;
}

__global__ __launch_bounds__(256) void knn_f32(const float* __restrict__ x,
                                               const float* __restrict__ sup,
                                               const float* __restrict__ s2g,
                                               float* __restrict__ pvals,
                                               int* __restrict__ pidx) {
    __shared__ float Xs[SBK][SLDT];
    __shared__ float Bs[SBK][SLDT];
    const int tid = threadIdx.x;
    const int tx = tid & 15, ty = tid >> 4;
    const int m0 = blockIdx.x * SBM, by = blockIdx.y;
    const int srow = tid >> 2, skq = (tid & 3) * 4;
    float rmin[8]; int ridx[8];
#pragma unroll
    for (int i = 0; i < 8; ++i) { rmin[i] = 3.4e38f; ridx[i] = 0x7fffffff; }
    const float* xr0 = x + (size_t)(m0 + srow) * DIM + skq;
    const float* xr1 = x + (size_t)(m0 + 64 + srow) * DIM + skq;
    for (int nt = 0; nt < SNT; ++nt) {
        const int n0 = (by * SNT + nt) * SBN;
        const float* sr0 = sup + (size_t)(n0 + srow) * DIM + skq;
        const float* sr1 = sup + (size_t)(n0 + 64 + srow) * DIM + skq;
        float acc[8][8];
#pragma unroll
        for (int i = 0; i < 8; ++i)
#pragma unroll
            for (int j = 0; j < 8; ++j) acc[i][j] = 0.0f;
        for (int kt = 0; kt < DIM / SBK; ++kt) {
            const int k0 = kt * SBK;
            float4 xv0 = *(const float4*)(xr0 + k0);
            float4 xv1 = *(const float4*)(xr1 + k0);
            float4 sv0 = *(const float4*)(sr0 + k0);
            float4 sv1 = *(const float4*)(sr1 + k0);
            __syncthreads();
            Xs[skq + 0][srow] = xv0.x; Xs[skq + 1][srow] = xv0.y;
            Xs[skq + 2][srow] = xv0.z; Xs[skq + 3][srow] = xv0.w;
            Xs[skq + 0][64 + srow] = xv1.x; Xs[skq + 1][64 + srow] = xv1.y;
            Xs[skq + 2][64 + srow] = xv1.z; Xs[skq + 3][64 + srow] = xv1.w;
            Bs[skq + 0][srow] = sv0.x; Bs[skq + 1][srow] = sv0.y;
            Bs[skq + 2][srow] = sv0.z; Bs[skq + 3][srow] = sv0.w;
            Bs[skq + 0][64 + srow] = sv1.x; Bs[skq + 1][64 + srow] = sv1.y;
            Bs[skq + 2][64 + srow] = sv1.z; Bs[skq + 3][64 + srow] = sv1.w;
            __syncthreads();
#pragma unroll
            for (int k = 0; k < SBK; ++k) {
                float4 a0 = *(const float4*)&Xs[k][ty * 4];
                float4 a1 = *(const float4*)&Xs[k][64 + ty * 4];
                float4 b0 = *(const float4*)&Bs[k][tx * 4];
                float4 b1 = *(const float4*)&Bs[k][64 + tx * 4];
                float a[8] = {a0.x, a0.y, a0.z, a0.w, a1.x, a1.y, a1.z, a1.w};
                float b[8] = {b0.x, b0.y, b0.z, b0.w, b1.x, b1.y, b1.z, b1.w};
#pragma unroll
                for (int i = 0; i < 8; ++i)
#pragma unroll
                    for (int j = 0; j < 8; ++j)
                        acc[i][j] = fmaf(a[i], b[j], acc[i][j]);
            }
        }
        const int nb0 = n0 + tx * 4, nb1 = n0 + 64 + tx * 4;
        float4 s20 = *(const float4*)(s2g + nb0);
        float4 s21 = *(const float4*)(s2g + nb1);
        float s2a[8] = {s20.x, s20.y, s20.z, s20.w, s21.x, s21.y, s21.z, s21.w};
        int nca[8] = {nb0, nb0 + 1, nb0 + 2, nb0 + 3, nb1, nb1 + 1, nb1 + 2, nb1 + 3};
#pragma unroll
        for (int i = 0; i < 8; ++i)
#pragma unroll
            for (int j = 0; j < 8; ++j) {
                float sc = fmaf(-2.0f, acc[i][j], s2a[j]);
                if (sc < rmin[i] || (sc == rmin[i] && nca[j] < ridx[i])) {
                    rmin[i] = sc; ridx[i] = nca[j];
                }
            }
    }
    __syncthreads();
    float* redv = (float*)Xs;
    int* redi = (int*)Bs;
#pragma unroll
    for (int i = 0; i < 8; ++i) {
        int mrow = (i < 4) ? (ty * 4 + i) : (64 + ty * 4 + (i - 4));
        redv[mrow * 16 + tx] = rmin[i];
        redi[mrow * 16 + tx] = ridx[i];
    }
    __syncthreads();
    if (tid < SBM) {
        float best = redv[tid * 16];
        int bi = redi[tid * 16];
#pragma unroll
        for (int t = 1; t < 16; ++t) {
            float v = redv[tid * 16 + t];
            int ix = redi[tid * 16 + t];
            if (v < best || (v == best && ix < bi)) { best = v; bi = ix; }
        }
        pvals[(size_t)(m0 + tid) * SGY + by] = best;
        pidx[(size_t)(m0 + tid) * SGY + by] = bi;
    }
}

__global__ __launch_bounds__(64) void finalize_f32(const float* __restrict__ pvals,
                                                   const int* __restrict__ pidx,
                                                   const int* __restrict__ labels,
                                                   const int* __restrict__ ncp,
                                                   int* __restrict__ out) {
    const int b = blockIdx.x, lane = threadIdx.x;
    float v = pvals[(size_t)b * SGY + lane];
    int ix = pidx[(size_t)b * SGY + lane];
#pragma unroll
    for (int off = 32; off > 0; off >>= 1) {
        float ov = __shfl_xor(v, off);
        int oi = __shfl_xor(ix, off);
        if (ov < v || (ov == v && oi < ix)) { v = ov; ix = oi; }
    }
    bool is64 = true;
    for (int i = 1; i < 128; i += 2)
        if (labels[i] != 0) { is64 = false; break; }
    const int lbl = is64 ? labels[2 * ix] : labels[ix];
    const int nc = ncp[0];
    for (int c = lane; c < nc; c += 64)
        out[b * nc + c] = (c == lbl) ? 1 : 0;
}

// ---------------------------------------------------------------------------
extern "C" void kernel_launch(void* const* d_in, const int* in_sizes, int n_in,
                              void* d_out, int out_size, void* d_ws, size_t ws_size,
                              hipStream_t stream) {
    const float* x      = (const float*)d_in[0];
    const float* sup    = (const float*)d_in[1];
    const int*   labels = (const int*)d_in[2];
    const int*   ncp    = (const int*)d_in[3];
    int* out = (int*)d_out;

    // fast-path workspace layout (~27 MB)
    char* p = (char*)d_ws;
    float* s2      = (float*)p;           p += (size_t)NS * 4;
    float* pv1     = (float*)p;           p += (size_t)BQ * GY * 4;
    float* pv2     = (float*)p;           p += (size_t)BQ * GY * 4;
    int*   pi1     = (int*)p;             p += (size_t)BQ * GY * 4;
    int*   fb_cnt  = (int*)p;             p += 256;   // padded
    int*   fb_list = (int*)p;             p += (size_t)BQ * 4;
    float* qbest   = (float*)p;           p += (size_t)BQ * 4;
    float* fb_v    = (float*)p;           p += (size_t)BQ * FBCH * 4;
    int*   fb_i    = (int*)p;             p += (size_t)BQ * FBCH * 4;
    f16*   xh      = (f16*)p;             p += (size_t)BQ * DIM * 2;
    f16*   sh      = (f16*)p;             p += (size_t)NS * DIM * 2;
    const size_t need = (size_t)(p - (char*)d_ws);

    if (ws_size >= need) {
        convert_kernel<<<NROWS / 4, 256, 0, stream>>>(x, sup, xh, sh, s2, fb_cnt);
        dim3 grid(BQ / BMQ, GY);
        knn_mfma<<<grid, 256, 0, stream>>>(xh, sh, s2, pv1, pv2, pi1);
        finalize2<<<BQ, 128, 0, stream>>>(pv1, pv2, pi1, labels, ncp, out,
                                          fb_cnt, fb_list, qbest);
        dim3 fbgrid(FBCH, 64);
        fallback_scan<<<fbgrid, 256, 0, stream>>>(x, sup, s2, fb_cnt, fb_list,
                                                  qbest, pv1, fb_v, fb_i);
        fallback_merge<<<64, 64, 0, stream>>>(fb_cnt, fb_list, fb_v, fb_i, labels, ncp, out);
    } else {
        // slow path: proven fp32 pipeline (R3)
        float* ss2   = (float*)d_ws;
        float* pvals = ss2 + NS;
        int*   pidx  = (int*)(pvals + (size_t)BQ * SGY);
        s2_kernel<<<NS / 4, 256, 0, stream>>>(sup, ss2);
        dim3 sgrid(BQ / SBM, SGY);
        knn_f32<<<sgrid, 256, 0, stream>>>(x, sup, ss2, pvals, pidx);
        finalize_f32<<<BQ, 64, 0, stream>>>(pvals, pidx, labels, ncp, out);
    }
}